// Round 2
// baseline (12.187 us; speedup 1.0000x reference)
//
#include <hip/hip_runtime.h>

__device__ __forceinline__ float sigf(float x) { return 1.0f / (1.0f + expf(-x)); }

__global__ __launch_bounds__(384) void net6max_kernel(
    const float* __restrict__ x,
    const float* __restrict__ W_ih_gen, const float* __restrict__ W_hh_gen,
    const float* __restrict__ b_ih_gen, const float* __restrict__ b_hh_gen,
    const float* __restrict__ h0_gen,  const float* __restrict__ c0_gen,
    const float* __restrict__ W_ih_game, const float* __restrict__ W_hh_game,
    const float* __restrict__ b_ih_game, const float* __restrict__ b_hh_game,
    const float* __restrict__ h0_game, const float* __restrict__ c0_game,
    const float* __restrict__ W1, const float* __restrict__ b1,
    const float* __restrict__ W2, const float* __restrict__ b2,
    const float* __restrict__ W3, const float* __restrict__ b3,
    float* __restrict__ out)
{
    __shared__ float hg[100];     // h_gen flat [k*10+j]
    __shared__ float hgame[250];  // h_game flat [o*50 + k*5 + j]
    __shared__ float avg_s[100];  // masked opponent average
    __shared__ float h1v[52];

    const int tid = threadIdx.x;

    // ---- t=0 prefetch: issue ALL late-phase global loads now (used after
    //      barriers; loads overlap the LSTM phase instead of serializing) ----
    float w1r[50];
    float b1r = 0.f;
    if (tid < 200) {
        const int row = tid >> 2, seg = tid & 3;
        const float* w = W1 + row * 200 + seg * 50;
        #pragma unroll
        for (int c = 0; c < 50; ++c) w1r[c] = w[c];
        if (seg == 0) b1r = b1[row];
    }
    float w2r[50];
    float b2r = 0.f, w3r = 0.f, b3r = 0.f;
    if (tid < 10) {
        const float* w = W2 + tid * 50;
        #pragma unroll
        for (int c = 0; c < 50; ++c) w2r[c] = w[c];
        b2r = b2[tid];
        w3r = W3[tid];
    }
    if (tid == 0) b3r = b3[0];

    // ---- phase A: both LSTMs, gates + activations fused (no barrier between) ----
    if (tid < 100) {              // gen cell (k, j): 4 gates, dot length 12+10
        const int k = tid / 10, j = tid % 10;
        float acc[4];
        #pragma unroll
        for (int g = 0; g < 4; ++g) {
            const int r = k * 40 + g * 10 + j;
            float s = b_ih_gen[r] + b_hh_gen[r];
            const float* wi = W_ih_gen + r * 12;
            #pragma unroll
            for (int i = 0; i < 12; ++i) s += wi[i] * x[i];
            const float* wh = W_hh_gen + r * 10;
            const float* h0 = h0_gen + k * 10;
            #pragma unroll
            for (int jj = 0; jj < 10; ++jj) s += wh[jj] * h0[jj];
            acc[g] = s;
        }
        const float c = sigf(acc[1]) * c0_gen[tid] + sigf(acc[0]) * tanhf(acc[2]);
        hg[tid] = sigf(acc[3]) * tanhf(c);
    }
    if (tid >= 128 && tid < 378) { // game cell (o, k, j): 4 gates, dot length 4+5
        const int e = tid - 128;
        const int o = e / 50, rem = e % 50, k = rem / 5, j = rem % 5;
        float acc[4];
        #pragma unroll
        for (int g = 0; g < 4; ++g) {
            const int r = k * 20 + g * 5 + j;
            float s = b_ih_game[r] + b_hh_game[r];
            const float* wi = W_ih_game + r * 4;
            const float* xi = x + 12 + o * 5 + 1;
            #pragma unroll
            for (int i = 0; i < 4; ++i) s += wi[i] * xi[i];
            const float* wh = W_hh_game + r * 5;
            const float* h0 = h0_game + (o * 10 + k) * 5;
            #pragma unroll
            for (int jj = 0; jj < 5; ++jj) s += wh[jj] * h0[jj];
            acc[g] = s;
        }
        const float c = sigf(acc[1]) * c0_game[e] + sigf(acc[0]) * tanhf(acc[2]);
        hgame[e] = sigf(acc[3]) * tanhf(c);
    }
    __syncthreads();

    // ---- phase C: masked opponent average (needs all hgame) ----
    if (tid < 100) {
        float cnt = 0.f, s = 0.f;
        #pragma unroll
        for (int o = 0; o < 5; ++o) {
            const float m = (truncf(x[12 + o * 5]) == 1.0f) ? 1.0f : 0.0f;
            cnt += m;
            const float f = (tid < 50) ? hgame[o * 50 + tid]
                                       : hgame[o * 50 + 45 + (tid - 50) % 5];
            s += m * f;
        }
        avg_s[tid] = (cnt > 0.f) ? (s / cnt) : 0.f;
    }
    __syncthreads();

    // ---- phase D: h1 = tanh([hg|avg] @ W1^T + b1), 4 lanes/row, W1 in regs ----
    if (tid < 200) {
        const int row = tid >> 2, seg = tid & 3;
        const float* v = (seg < 2) ? (hg + seg * 50) : (avg_s + (seg - 2) * 50);
        float p = 0.f;
        #pragma unroll
        for (int c = 0; c < 50; ++c) p += w1r[c] * v[c];
        p += __shfl_down(p, 2);   // 4-aligned groups stay inside the 64-lane wave
        p += __shfl_down(p, 1);
        if (seg == 0) h1v[row] = tanhf(p + b1r);
    }
    __syncthreads();

    // ---- phase E+F: final two layers inside wave 0 (wave-synchronous, no barrier) ----
    if (tid < 64) {
        float h2 = 0.f;
        if (tid < 10) {
            float s = b2r;
            #pragma unroll
            for (int c = 0; c < 50; ++c) s += w2r[c] * h1v[c];
            h2 = tanhf(s);
        }
        float p = (tid < 10) ? w3r * h2 : 0.f;
        p += __shfl_xor(p, 8);    // sum over lanes 0..15 (lanes 10..15 contribute 0)
        p += __shfl_xor(p, 4);
        p += __shfl_xor(p, 2);
        p += __shfl_xor(p, 1);
        if (tid == 0) out[0] = tanhf(p + b3r);
    }
}

extern "C" void kernel_launch(void* const* d_in, const int* in_sizes, int n_in,
                              void* d_out, int out_size, void* d_ws, size_t ws_size,
                              hipStream_t stream) {
    (void)in_sizes; (void)n_in; (void)out_size; (void)d_ws; (void)ws_size;
    net6max_kernel<<<1, 384, 0, stream>>>(
        (const float*)d_in[0],  // x
        (const float*)d_in[1],  // W_ih_gen
        (const float*)d_in[2],  // W_hh_gen
        (const float*)d_in[3],  // b_ih_gen
        (const float*)d_in[4],  // b_hh_gen
        (const float*)d_in[5],  // h0_gen
        (const float*)d_in[6],  // c0_gen
        (const float*)d_in[7],  // W_ih_game
        (const float*)d_in[8],  // W_hh_game
        (const float*)d_in[9],  // b_ih_game
        (const float*)d_in[10], // b_hh_game
        (const float*)d_in[11], // h0_game
        (const float*)d_in[12], // c0_game
        (const float*)d_in[13], // W1
        (const float*)d_in[14], // b1
        (const float*)d_in[15], // W2
        (const float*)d_in[16], // b2
        (const float*)d_in[17], // W3
        (const float*)d_in[18], // b3
        (float*)d_out);
}

// Round 3
// 11.287 us; speedup vs baseline: 1.0798x; 1.0798x over previous
//
#include <hip/hip_runtime.h>

__device__ __forceinline__ float sigf(float x) { return 1.0f / (1.0f + expf(-x)); }

__global__ __launch_bounds__(512) void net6max_kernel(
    const float* __restrict__ x,
    const float* __restrict__ W_ih_gen, const float* __restrict__ W_hh_gen,
    const float* __restrict__ b_ih_gen, const float* __restrict__ b_hh_gen,
    const float* __restrict__ h0_gen,  const float* __restrict__ c0_gen,
    const float* __restrict__ W_ih_game, const float* __restrict__ W_hh_game,
    const float* __restrict__ b_ih_game, const float* __restrict__ b_hh_game,
    const float* __restrict__ h0_game, const float* __restrict__ c0_game,
    const float* __restrict__ W1, const float* __restrict__ b1,
    const float* __restrict__ W2, const float* __restrict__ b2,
    const float* __restrict__ W3, const float* __restrict__ b3,
    float* __restrict__ out)
{
    __shared__ __align__(16) float hg[100];     // h_gen flat [k*10+j]
    __shared__ __align__(16) float hgame[250];  // h_game flat [o*50+k*5+j]
    __shared__ __align__(16) float avg_s[100];  // masked opponent average
    __shared__ __align__(16) float h1v[52];

    const int tid = threadIdx.x;

    // ================= Phase A: both LSTMs, gate-per-thread =================
    // gen: threads 0..399, 1 gate each; cell = tid>>2, gate = tid&3
    float s_gen = 0.f, c0g = 0.f;
    if (tid < 400) {
        const int cell = tid >> 2, g = tid & 3;
        const int k = cell / 10, j = cell % 10;
        const int r = k * 40 + g * 10 + j;
        const float4* wi4 = (const float4*)(W_ih_gen + r * 12);   // r*48B, 16B-aligned
        const float4* x4  = (const float4*)x;
        const float4 wa = wi4[0], wb = wi4[1], wc = wi4[2];
        const float4 xa = x4[0],  xb = x4[1],  xc = x4[2];
        float s = b_ih_gen[r] + b_hh_gen[r];
        s += wa.x*xa.x + wa.y*xa.y + wa.z*xa.z + wa.w*xa.w;
        s += wb.x*xb.x + wb.y*xb.y + wb.z*xb.z + wb.w*xb.w;
        s += wc.x*xc.x + wc.y*xc.y + wc.z*xc.z + wc.w*xc.w;
        const float2* wh2 = (const float2*)(W_hh_gen + r * 10);   // 8B-aligned
        const float2* h02 = (const float2*)(h0_gen + k * 10);
        #pragma unroll
        for (int q = 0; q < 5; ++q) {
            const float2 w = wh2[q], h = h02[q];
            s += w.x*h.x + w.y*h.y;
        }
        s_gen = s;
        if (g == 0) c0g = c0_gen[cell];
    }

    // game: threads 0..499, 2 gates each; cell = tid>>1, half = tid&1
    float su = 0.f, sv = 0.f, c0gm = 0.f;
    if (tid < 500) {
        const int c2 = tid >> 1, half = tid & 1;
        const int o = c2 / 50, rem = c2 % 50, k = rem / 5, j = rem % 5;
        const float* xi = x + 12 + o * 5 + 1;
        const float x0 = xi[0], x1 = xi[1], x2 = xi[2], x3 = xi[3];
        const float* h0 = h0_game + (o * 10 + k) * 5;
        const float h00 = h0[0], h01 = h0[1], h02v = h0[2], h03 = h0[3], h04 = h0[4];
        #pragma unroll
        for (int gg = 0; gg < 2; ++gg) {
            const int g = half * 2 + gg;
            const int r = k * 20 + g * 5 + j;
            const float4 wi = *(const float4*)(W_ih_game + r * 4); // r*16B aligned
            float s = b_ih_game[r] + b_hh_game[r];
            s += wi.x*x0 + wi.y*x1 + wi.z*x2 + wi.w*x3;
            const float* wh = W_hh_game + r * 5;
            s += wh[0]*h00 + wh[1]*h01 + wh[2]*h02v + wh[3]*h03 + wh[4]*h04;
            if (gg == 0) su = s; else sv = s;
        }
        if (half == 0) c0gm = c0_game[c2];
    }

    // ---- prefetch late-phase weights now (needed only after barrier 2/3;
    //      loads overlap the LSTM activations below) ----
    float2 w1r[25]; float b1r = 0.f;
    if (tid < 200) {
        const int row = tid >> 2, seg = tid & 3;
        const float2* w = (const float2*)(W1 + row * 200 + seg * 50); // 8B-aligned
        #pragma unroll
        for (int q = 0; q < 25; ++q) w1r[q] = w[q];
        if (seg == 0) b1r = b1[row];
    }
    float2 w2r[25]; float b2r = 0.f, w3r = 0.f, b3r = 0.f;
    if (tid < 10) {
        const float2* w = (const float2*)(W2 + tid * 50);
        #pragma unroll
        for (int q = 0; q < 25; ++q) w2r[q] = w[q];
        b2r = b2[tid];
        w3r = W3[tid];
    }
    if (tid == 0) b3r = b3[0];

    // ---- activations distributed across lanes, combine via shuffles ----
    // gen: lane g holds gate g; g==2 needs tanh, others sigmoid
    {
        const float a  = ((tid & 3) == 2) ? tanhf(s_gen) : sigf(s_gen);
        const float a1 = __shfl_xor(a, 1);   // gate f   (for lane g==0)
        const float a2 = __shfl_xor(a, 2);   // gate g~
        const float a3 = __shfl_xor(a, 3);   // gate o
        if (tid < 400 && (tid & 3) == 0) {
            const float c = a1 * c0g + a * a2;
            hg[tid >> 2] = a3 * tanhf(c);
        }
    }
    // game: even lane holds (sig_i, sig_f); odd lane holds (tanh_g, sig_o)
    {
        const float u = ((tid & 1) == 0) ? sigf(su) : tanhf(su);
        const float v = sigf(sv);
        const float up = __shfl_xor(u, 1);
        const float vp = __shfl_xor(v, 1);
        if (tid < 500 && (tid & 1) == 0) {
            const float c = v * c0gm + u * up;   // sig_f*c0 + sig_i*tanh_g
            hgame[tid >> 1] = vp * tanhf(c);     // sig_o * tanh(c)
        }
    }
    __syncthreads();   // barrier 1

    // ================= Phase C: masked opponent average =================
    if (tid < 100) {
        float cnt = 0.f, s = 0.f;
        #pragma unroll
        for (int o = 0; o < 5; ++o) {
            const float m = (truncf(x[12 + o * 5]) == 1.0f) ? 1.0f : 0.0f;
            cnt += m;
            const float f = (tid < 50) ? hgame[o * 50 + tid]
                                       : hgame[o * 50 + 45 + (tid - 50) % 5];
            s += m * f;
        }
        avg_s[tid] = (cnt > 0.f) ? (s / cnt) : 0.f;
    }
    __syncthreads();   // barrier 2

    // ================= Phase D: h1 = tanh([hg|avg] @ W1^T + b1) =================
    if (tid < 200) {
        const int row = tid >> 2, seg = tid & 3;
        const float2* v2 = (seg < 2) ? (const float2*)(hg + seg * 50)
                                     : (const float2*)(avg_s + (seg - 2) * 50);
        float p = 0.f;
        #pragma unroll
        for (int q = 0; q < 25; ++q) p += w1r[q].x * v2[q].x + w1r[q].y * v2[q].y;
        p += __shfl_down(p, 2);   // 4-aligned groups stay inside the 64-lane wave
        p += __shfl_down(p, 1);
        if (seg == 0) h1v[row] = tanhf(p + b1r);
    }
    __syncthreads();   // barrier 3

    // ================= Phase E+F: final two layers in wave 0 =================
    if (tid < 64) {
        float h2 = 0.f;
        if (tid < 10) {
            float s = b2r;
            const float2* h1v2 = (const float2*)h1v;
            #pragma unroll
            for (int q = 0; q < 25; ++q) s += w2r[q].x * h1v2[q].x + w2r[q].y * h1v2[q].y;
            h2 = tanhf(s);
        }
        float p = (tid < 10) ? w3r * h2 : 0.f;
        p += __shfl_xor(p, 8);
        p += __shfl_xor(p, 4);
        p += __shfl_xor(p, 2);
        p += __shfl_xor(p, 1);
        if (tid == 0) out[0] = tanhf(p + b3r);
    }
}

extern "C" void kernel_launch(void* const* d_in, const int* in_sizes, int n_in,
                              void* d_out, int out_size, void* d_ws, size_t ws_size,
                              hipStream_t stream) {
    (void)in_sizes; (void)n_in; (void)out_size; (void)d_ws; (void)ws_size;
    net6max_kernel<<<1, 512, 0, stream>>>(
        (const float*)d_in[0],  // x
        (const float*)d_in[1],  // W_ih_gen
        (const float*)d_in[2],  // W_hh_gen
        (const float*)d_in[3],  // b_ih_gen
        (const float*)d_in[4],  // b_hh_gen
        (const float*)d_in[5],  // h0_gen
        (const float*)d_in[6],  // c0_gen
        (const float*)d_in[7],  // W_ih_game
        (const float*)d_in[8],  // W_hh_game
        (const float*)d_in[9],  // b_ih_game
        (const float*)d_in[10], // b_hh_game
        (const float*)d_in[11], // h0_game
        (const float*)d_in[12], // c0_game
        (const float*)d_in[13], // W1
        (const float*)d_in[14], // b1
        (const float*)d_in[15], // W2
        (const float*)d_in[16], // b2
        (const float*)d_in[17], // W3
        (const float*)d_in[18], // b3
        (float*)d_out);
}